// Round 6
// baseline (11208.538 us; speedup 1.0000x reference)
//
#include <hip/hip_runtime.h>
#include <hip/hip_cooperative_groups.h>
#include <math.h>

namespace cg = cooperative_groups;

#define Tsz 512
#define NBLK 256
#define NTHR 512

// LDS pitches in shorts; dword pitch odd -> MFMA fragment reads ~2-way (free)
#define PA0 330   // L0 A rows, 320 used   (165 dw)
#define PA1 522   // L1 A rows, 512 used   (261 dw)
#define PB0 330   // B h0|x rows, 320 used (165 dw)
#define PB1 266   // B h1 rows, 256 used   (133 dw)
#define A1B 10560 // 32*PA0
#define B1B 5280  // 16*PB0

typedef short short8  __attribute__((ext_vector_type(8)));
typedef short short4v __attribute__((ext_vector_type(4)));
typedef float float4v __attribute__((ext_vector_type(4)));

#define MFMA16(a, b, c) __builtin_amdgcn_mfma_f32_16x16x32_bf16((a), (b), (c), 0, 0, 0)

__device__ __forceinline__ float sigm(float x) { return 1.0f / (1.0f + __expf(-x)); }
__device__ __forceinline__ float tanh_fast(float x) { return 2.0f / (1.0f + __expf(-2.0f * x)) - 1.0f; }

// fp32 -> bf16 hi (x) + bf16 lo (y), RNE both: v ~= hi + lo, error ~2^-17 rel
__device__ __forceinline__ short2 split1(float f) {
    unsigned u = __float_as_uint(f);
    unsigned r = u + 0x7FFFu + ((u >> 16) & 1u);
    short h = (short)(r >> 16);
    float hf = __uint_as_float(r & 0xFFFF0000u);
    float d  = f - hf;
    unsigned u2 = __float_as_uint(d);
    unsigned r2 = u2 + 0x7FFFu + ((u2 >> 16) & 1u);
    return make_short2(h, (short)(r2 >> 16));
}

// Weight-stationary 2-layer LSTM via bf16-split-3 MFMA.
// 256 blocks = 32 row-slices (8 cols) x 8 batch-slices (32 batches, 2 passes of 16).
// M=64 rows (L0 rows 0..31, L1 rows 32..63), N=16, K: L0=320 (h0|x), L1=512 (h0|h1).
// 4 16x16 tiles x 2 k-halves = 8 waves; z = Ah*Bh + Ah*Bl + Al*Bh (lo*lo dropped).
// Per-bs 32-block barrier: padded per-group counter (1KB apart) + s_sleep(8) backoff.
__global__ __launch_bounds__(NTHR, 1)
void lstm2_mfma(const float* __restrict__ x,
                const float* __restrict__ Wih0, const float* __restrict__ Whh0,
                const float* __restrict__ bih0, const float* __restrict__ bhh0,
                const float* __restrict__ Wih1, const float* __restrict__ Whh1,
                const float* __restrict__ bih1, const float* __restrict__ bhh1,
                const float* __restrict__ Wf,   const float* __restrict__ bf,
                float* __restrict__ out, float* __restrict__ ws)
{
    cg::grid_group grid = cg::this_grid();
    const int tid = threadIdx.x;
    const int rs  = blockIdx.x >> 3;
    const int bs  = blockIdx.x & 7;

    __shared__ short Wh[2][27264];          // 109.1 KB (L0: 32*PA0, L1: 32*PA1)
    __shared__ short Bh[2][9536];           // 38.1 KB  (h0|x: 16*PB0, h1: 16*PB1)
    __shared__ float zpart[4][64][4];       // 4 KB
    __shared__ float zf[64][17];            // 4.3 KB

    float* h0buf = ws;                          // [2][256 batch][256 col]
    float* h1buf = ws + 2 * 256 * 256;
    unsigned* cnt = (unsigned*)(ws + 4 * 256 * 256);   // counter bs at cnt[bs*256] (1KB apart)

    // ---- init ----
    for (int i = blockIdx.x * NTHR + tid; i < 4 * 256 * 256; i += NBLK * NTHR) ws[i] = 0.f;
    if (rs == 0 && tid == 0) cnt[bs * 256] = 0u;
    if (rs == 0 && tid < 32) out[bs * 32 + tid] = bf[0];

    // ---- one-time weight stage: fp32 -> hi/lo bf16 planes ----
    for (int m = 0; m < 64; ++m) {
        const int L = m >> 5, wr = m & 31, g = wr >> 3, cc = wr & 7;
        const size_t grow = (size_t)(g * 256 + rs * 8 + cc);
        const int klen = L ? 512 : 320;
        const int base = L ? A1B + (m - 32) * PA1 : m * PA0;
        for (int k = tid; k < klen; k += NTHR) {
            float w;
            if (!L) w = (k < 256) ? Whh0[grow * 256 + k] : Wih0[grow * 64 + (k - 256)];
            else    w = (k < 256) ? Wih1[grow * 256 + k] : Whh1[grow * 256 + (k - 256)];
            short2 hl = split1(w);
            Wh[0][base + k] = hl.x; Wh[1][base + k] = hl.y;
        }
    }

    // ---- mfma lane decode ----
    const int wv = tid >> 6, lane = tid & 63;
    const int mt = wv & 3, half = wv >> 2;          // tile, k-half
    const int quad = lane >> 4, n16 = lane & 15;
    const int rowA = 16 * mt + n16;
    const int aBase = (rowA < 32 ? rowA * PA0 : A1B + (rowA - 32) * PA1) + quad * 8;
    const int bBase0 = n16 * PB0 + quad * 8;
    const int bBase1 = B1B + n16 * PB1 + quad * 8;

    // ---- updater decode (tid < 256): layer ul, col ucc, batch ub ----
    const int ul = tid >> 7, ucc = tid & 7, ub = (tid >> 3) & 15;
    const int ucol = rs * 8 + ucc;
    float ubias[4];
    if (tid < 256) {
        const float* bi = ul ? bih1 : bih0;
        const float* bh = ul ? bhh1 : bhh0;
        #pragma unroll
        for (int g = 0; g < 4; ++g) ubias[g] = bi[g * 256 + ucol] + bh[g * 256 + ucol];
    }
    float c0[2] = {0.f, 0.f}, c1[2] = {0.f, 0.f}, h1last[2] = {0.f, 0.f};

    grid.sync();

    for (int s = 0; s <= Tsz; ++s) {
        const int rp = (s + 1) & 1;   // parity of h0[s-1]
        const int rq = s & 1;         // parity of h1[s-2]
        #pragma unroll
        for (int p = 0; p < 2; ++p) {
            const int bbase = bs * 32 + p * 16;

            // ---- stage h0[s-1], h1[s-2], x[.,s,.] -> hi/lo bf16 B-planes ----
            {
                const int sn = tid >> 5, sk = (tid & 31) * 8;
                const float* p0 = &h0buf[((size_t)(rp * 256) + bbase + sn) * 256 + sk];
                float4 a = *(const float4*)p0, b = *(const float4*)(p0 + 4);
                short8 hi, lo;
                short2 t;
                t = split1(a.x); hi[0] = t.x; lo[0] = t.y;
                t = split1(a.y); hi[1] = t.x; lo[1] = t.y;
                t = split1(a.z); hi[2] = t.x; lo[2] = t.y;
                t = split1(a.w); hi[3] = t.x; lo[3] = t.y;
                t = split1(b.x); hi[4] = t.x; lo[4] = t.y;
                t = split1(b.y); hi[5] = t.x; lo[5] = t.y;
                t = split1(b.z); hi[6] = t.x; lo[6] = t.y;
                t = split1(b.w); hi[7] = t.x; lo[7] = t.y;
                *(short8*)&Bh[0][sn * PB0 + sk] = hi;
                *(short8*)&Bh[1][sn * PB0 + sk] = lo;
                const float* p1 = &h1buf[((size_t)(rq * 256) + bbase + sn) * 256 + sk];
                a = *(const float4*)p1; b = *(const float4*)(p1 + 4);
                t = split1(a.x); hi[0] = t.x; lo[0] = t.y;
                t = split1(a.y); hi[1] = t.x; lo[1] = t.y;
                t = split1(a.z); hi[2] = t.x; lo[2] = t.y;
                t = split1(a.w); hi[3] = t.x; lo[3] = t.y;
                t = split1(b.x); hi[4] = t.x; lo[4] = t.y;
                t = split1(b.y); hi[5] = t.x; lo[5] = t.y;
                t = split1(b.z); hi[6] = t.x; lo[6] = t.y;
                t = split1(b.w); hi[7] = t.x; lo[7] = t.y;
                *(short8*)&Bh[0][B1B + sn * PB1 + sk] = hi;
                *(short8*)&Bh[1][B1B + sn * PB1 + sk] = lo;
            }
            if (s < Tsz && tid < 256) {
                const int xn = tid >> 4, d4 = (tid & 15) * 4;
                float4 xv = *(const float4*)&x[((size_t)(bbase + xn) * Tsz + s) * 64 + d4];
                short4v xh, xl;
                short2 t;
                t = split1(xv.x); xh[0] = t.x; xl[0] = t.y;
                t = split1(xv.y); xh[1] = t.x; xl[1] = t.y;
                t = split1(xv.z); xh[2] = t.x; xl[2] = t.y;
                t = split1(xv.w); xh[3] = t.x; xl[3] = t.y;
                *(short4v*)&Bh[0][xn * PB0 + 256 + d4] = xh;
                *(short4v*)&Bh[1][xn * PB0 + 256 + d4] = xl;
            }
            __syncthreads();   // S1

            // ---- MFMA: 16x16 tile mt, k-half ----
            float4v acc = {0.f, 0.f, 0.f, 0.f};
            if (mt < 2) {                       // layer 0: K=320, chunks half*5..+5
                const int k0 = half * 5 * 32;
                #pragma unroll
                for (int kc = 0; kc < 5; ++kc) {
                    const int ao = aBase + k0 + kc * 32;
                    const int bo = bBase0 + k0 + kc * 32;
                    short8 ah = *(const short8*)&Wh[0][ao];
                    short8 al = *(const short8*)&Wh[1][ao];
                    short8 bh2 = *(const short8*)&Bh[0][bo];
                    short8 bl2 = *(const short8*)&Bh[1][bo];
                    acc = MFMA16(ah, bh2, acc);
                    acc = MFMA16(ah, bl2, acc);
                    acc = MFMA16(al, bh2, acc);
                }
            } else if (half == 0) {             // layer 1, k 0..255 vs h0
                #pragma unroll
                for (int kc = 0; kc < 8; ++kc) {
                    const int ao = aBase + kc * 32;
                    const int bo = bBase0 + kc * 32;
                    short8 ah = *(const short8*)&Wh[0][ao];
                    short8 al = *(const short8*)&Wh[1][ao];
                    short8 bh2 = *(const short8*)&Bh[0][bo];
                    short8 bl2 = *(const short8*)&Bh[1][bo];
                    acc = MFMA16(ah, bh2, acc);
                    acc = MFMA16(ah, bl2, acc);
                    acc = MFMA16(al, bh2, acc);
                }
            } else {                            // layer 1, k 256..511 vs h1
                #pragma unroll
                for (int kc = 0; kc < 8; ++kc) {
                    const int ao = aBase + 256 + kc * 32;
                    const int bo = bBase1 + kc * 32;
                    short8 ah = *(const short8*)&Wh[0][ao];
                    short8 al = *(const short8*)&Wh[1][ao];
                    short8 bh2 = *(const short8*)&Bh[0][bo];
                    short8 bl2 = *(const short8*)&Bh[1][bo];
                    acc = MFMA16(ah, bh2, acc);
                    acc = MFMA16(ah, bl2, acc);
                    acc = MFMA16(al, bh2, acc);
                }
            }

            // ---- k-half combine + zf scatter ----
            if (half) *(float4v*)&zpart[mt][lane][0] = acc;
            __syncthreads();   // S2
            if (!half) {
                acc += *(const float4v*)&zpart[mt][lane][0];
                #pragma unroll
                for (int r = 0; r < 4; ++r)
                    zf[16 * mt + quad * 4 + r][n16] = acc[r];
            }
            __syncthreads();   // S3

            // ---- cell update ----
            if (tid < 256) {
                const bool active = ul ? (s >= 1) : (s < Tsz);
                if (active) {
                    const int mb = ul * 32 + ucc;
                    float z0 = zf[mb +  0][ub] + ubias[0];
                    float z1 = zf[mb +  8][ub] + ubias[1];
                    float z2 = zf[mb + 16][ub] + ubias[2];
                    float z3 = zf[mb + 24][ub] + ubias[3];
                    float ii = sigm(z0), ff = sigm(z1);
                    float gg = tanh_fast(z2), oo = sigm(z3);
                    if (ul) {
                        float c = ff * c1[p] + ii * gg; c1[p] = c;
                        float h = oo * tanh_fast(c);
                        h1last[p] = h;
                        h1buf[((size_t)(((s + 1) & 1) * 256) + bbase + ub) * 256 + ucol] = h;
                    } else {
                        float c = ff * c0[p] + ii * gg; c0[p] = c;
                        h0buf[((size_t)((s & 1) * 256) + bbase + ub) * 256 + ucol] =
                            oo * tanh_fast(c);
                    }
                }
            }
            // safe: next stage rewrites Bh only after S1; zpart/zf rewritten after S2.
        }

        // ---- 32-block group barrier: padded per-group counter ----
        __syncthreads();
        if (tid == 0) {
            __threadfence();                                   // release h writes
            atomicAdd(&cnt[bs * 256], 1u);
            const unsigned tgt = 32u * (unsigned)(s + 1);
            while (__hip_atomic_load(&cnt[bs * 256], __ATOMIC_RELAXED,
                                     __HIP_MEMORY_SCOPE_AGENT) < tgt)
                __builtin_amdgcn_s_sleep(8);
            __threadfence();                                   // acquire
        }
        __syncthreads();
    }

    // ---- epilogue ----
    if (tid >= 128 && tid < 256) {
        const float wf = Wf[ucol];
        atomicAdd(&out[bs * 32 + ub],      h1last[0] * wf);
        atomicAdd(&out[bs * 32 + 16 + ub], h1last[1] * wf);
    }
}

extern "C" void kernel_launch(void* const* d_in, const int* in_sizes, int n_in,
                              void* d_out, int out_size, void* d_ws, size_t ws_size,
                              hipStream_t stream) {
    const float* x    = (const float*)d_in[0];
    const float* Wih0 = (const float*)d_in[1];
    const float* Whh0 = (const float*)d_in[2];
    const float* bih0 = (const float*)d_in[3];
    const float* bhh0 = (const float*)d_in[4];
    const float* Wih1 = (const float*)d_in[5];
    const float* Whh1 = (const float*)d_in[6];
    const float* bih1 = (const float*)d_in[7];
    const float* bhh1 = (const float*)d_in[8];
    const float* Wf   = (const float*)d_in[9];
    const float* bf   = (const float*)d_in[10];
    float* out = (float*)d_out;
    float* ws  = (float*)d_ws;   // 1 MB h buffers + 8 KB padded barrier counters

    void* args[] = {
        (void*)&x, (void*)&Wih0, (void*)&Whh0, (void*)&bih0, (void*)&bhh0,
        (void*)&Wih1, (void*)&Whh1, (void*)&bih1, (void*)&bhh1,
        (void*)&Wf, (void*)&bf, (void*)&out, (void*)&ws
    };
    hipLaunchCooperativeKernel((void*)lstm2_mfma, dim3(NBLK), dim3(NTHR),
                               args, 0, stream);
}

// Round 7
// 7155.556 us; speedup vs baseline: 1.5664x; 1.5664x over previous
//
#include <hip/hip_runtime.h>
#include <hip/hip_cooperative_groups.h>
#include <math.h>

namespace cg = cooperative_groups;

#define Tsz 512
#define NBLK 256
#define NTHR 512

// Unpadded LDS pitches (shorts). All ≡ 0 mod 32 dwords — matches m97's measured
// conflict-free ds_read_b128 fragment pattern. (Padded pitches made conflicts WORSE:
// R5 ≡4: 2.35e8, R6 ≡5: 4.37e8 — the scalar-dword bank model does not apply to b128.)
#define PA0 320   // L0 A rows (K=320: h0|x)
#define PA1 512   // L1 A rows (K=512: h0|h1)
#define PB0 320   // B h0|x rows
#define PB1 256   // B h1 rows
#define A1B 10240 // 32*PA0
#define B1B 5120  // 16*PB0

typedef short short8  __attribute__((ext_vector_type(8)));
typedef short short4v __attribute__((ext_vector_type(4)));
typedef float float4v __attribute__((ext_vector_type(4)));

#define MFMA16(a, b, c) __builtin_amdgcn_mfma_f32_16x16x32_bf16((a), (b), (c), 0, 0, 0)
#define LOADX(p) __hip_atomic_load((p), __ATOMIC_RELAXED, __HIP_MEMORY_SCOPE_AGENT)
#define STOREX(p, v) __hip_atomic_store((p), (v), __ATOMIC_RELAXED, __HIP_MEMORY_SCOPE_AGENT)

__device__ __forceinline__ float sigm(float x) { return 1.0f / (1.0f + __expf(-x)); }
__device__ __forceinline__ float tanh_fast(float x) { return 2.0f / (1.0f + __expf(-2.0f * x)) - 1.0f; }

// fp32 -> bf16 hi (x) + bf16 lo (y), RNE both: v ~= hi + lo, error ~2^-17 rel
__device__ __forceinline__ short2 split1(float f) {
    unsigned u = __float_as_uint(f);
    unsigned r = u + 0x7FFFu + ((u >> 16) & 1u);
    short h = (short)(r >> 16);
    float hf = __uint_as_float(r & 0xFFFF0000u);
    float d  = f - hf;
    unsigned u2 = __float_as_uint(d);
    unsigned r2 = u2 + 0x7FFFu + ((u2 >> 16) & 1u);
    return make_short2(h, (short)(r2 >> 16));
}

// Weight-stationary 2-layer LSTM via bf16-split-3 MFMA.
// 256 blocks = 32 row-slices (8 cols) x 8 batch-slices (32 batches, 2 passes of 16).
// h exchange: device-scope relaxed atomics (no fences, no L2 writeback/invalidate);
// per-group barrier: counter + broadcast epoch flag, last-arriver publishes.
__global__ __launch_bounds__(NTHR, 1)
void lstm2_mfma(const float* __restrict__ x,
                const float* __restrict__ Wih0, const float* __restrict__ Whh0,
                const float* __restrict__ bih0, const float* __restrict__ bhh0,
                const float* __restrict__ Wih1, const float* __restrict__ Whh1,
                const float* __restrict__ bih1, const float* __restrict__ bhh1,
                const float* __restrict__ Wf,   const float* __restrict__ bf,
                float* __restrict__ out, float* __restrict__ ws)
{
    cg::grid_group grid = cg::this_grid();
    const int tid = threadIdx.x;
    const int rs  = blockIdx.x >> 3;
    const int bs  = blockIdx.x & 7;

    __shared__ short Wh[2][26624];          // 106.5 KB (L0: 32*PA0, L1: 32*PA1)
    __shared__ short Bh[2][9216];           // 36.9 KB  (h0|x: 16*PB0, h1: 16*PB1)
    __shared__ float zpart[4][64][4];       // 4 KB
    __shared__ float zf[64][17];            // 4.3 KB (b32 access: +1 pad valid here)

    float* h0buf = ws;                          // [2][256 batch][256 col]
    float* h1buf = ws + 2 * 256 * 256;
    unsigned* syn = (unsigned*)(ws + 4 * 256 * 256);
    // counter for group bs: syn[bs*256]; epoch flag: syn[2048 + bs*256] (1KB apart each)

    // ---- init ----
    for (int i = blockIdx.x * NTHR + tid; i < 4 * 256 * 256; i += NBLK * NTHR) ws[i] = 0.f;
    if (rs == 0 && tid == 0) { syn[bs * 256] = 0u; syn[2048 + bs * 256] = 0u; }
    if (rs == 0 && tid < 32) out[bs * 32 + tid] = bf[0];

    // ---- one-time weight stage: fp32 -> hi/lo bf16 planes ----
    for (int m = 0; m < 64; ++m) {
        const int L = m >> 5, wr = m & 31, g = wr >> 3, cc = wr & 7;
        const size_t grow = (size_t)(g * 256 + rs * 8 + cc);
        const int klen = L ? 512 : 320;
        const int base = L ? A1B + (m - 32) * PA1 : m * PA0;
        for (int k = tid; k < klen; k += NTHR) {
            float w;
            if (!L) w = (k < 256) ? Whh0[grow * 256 + k] : Wih0[grow * 64 + (k - 256)];
            else    w = (k < 256) ? Wih1[grow * 256 + k] : Whh1[grow * 256 + (k - 256)];
            short2 hl = split1(w);
            Wh[0][base + k] = hl.x; Wh[1][base + k] = hl.y;
        }
    }

    // ---- mfma lane decode ----
    const int wv = tid >> 6, lane = tid & 63;
    const int mt = wv & 3, half = wv >> 2;          // tile, k-half
    const int quad = lane >> 4, n16 = lane & 15;
    const int rowA = 16 * mt + n16;
    const int aBase = (rowA < 32 ? rowA * PA0 : A1B + (rowA - 32) * PA1) + quad * 8;
    const int bBase0 = n16 * PB0 + quad * 8;
    const int bBase1 = B1B + n16 * PB1 + quad * 8;

    // ---- updater decode (tid < 256): layer ul, col ucc, batch ub ----
    const int ul = tid >> 7, ucc = tid & 7, ub = (tid >> 3) & 15;
    const int ucol = rs * 8 + ucc;
    float ubias[4];
    if (tid < 256) {
        const float* bi = ul ? bih1 : bih0;
        const float* bh = ul ? bhh1 : bhh0;
        #pragma unroll
        for (int g = 0; g < 4; ++g) ubias[g] = bi[g * 256 + ucol] + bh[g * 256 + ucol];
    }
    float c0[2] = {0.f, 0.f}, c1[2] = {0.f, 0.f}, h1last[2] = {0.f, 0.f};

    grid.sync();   // init + weights visible device-wide

    for (int s = 0; s <= Tsz; ++s) {
        const int rp = (s + 1) & 1;   // parity of h0[s-1]
        const int rq = s & 1;         // parity of h1[s-2]
        #pragma unroll
        for (int p = 0; p < 2; ++p) {
            const int bbase = bs * 32 + p * 16;

            // ---- stage h0[s-1], h1[s-2], x[.,s,.] -> hi/lo bf16 B-planes ----
            {
                const int sn = tid >> 5, sk = (tid & 31) * 8;
                const float* p0 = &h0buf[((size_t)(rp * 256) + bbase + sn) * 256 + sk];
                const float* p1 = &h1buf[((size_t)(rq * 256) + bbase + sn) * 256 + sk];
                float v0[8], v1[8];
                #pragma unroll
                for (int i = 0; i < 8; ++i) v0[i] = LOADX(p0 + i);
                #pragma unroll
                for (int i = 0; i < 8; ++i) v1[i] = LOADX(p1 + i);
                short8 hi, lo;
                #pragma unroll
                for (int i = 0; i < 8; ++i) {
                    short2 t = split1(v0[i]); hi[i] = t.x; lo[i] = t.y;
                }
                *(short8*)&Bh[0][sn * PB0 + sk] = hi;
                *(short8*)&Bh[1][sn * PB0 + sk] = lo;
                #pragma unroll
                for (int i = 0; i < 8; ++i) {
                    short2 t = split1(v1[i]); hi[i] = t.x; lo[i] = t.y;
                }
                *(short8*)&Bh[0][B1B + sn * PB1 + sk] = hi;
                *(short8*)&Bh[1][B1B + sn * PB1 + sk] = lo;
            }
            if (s < Tsz && tid < 256) {
                const int xn = tid >> 4, d4 = (tid & 15) * 4;
                float4 xv = *(const float4*)&x[((size_t)(bbase + xn) * Tsz + s) * 64 + d4];
                short4v xh, xl;
                short2 t;
                t = split1(xv.x); xh[0] = t.x; xl[0] = t.y;
                t = split1(xv.y); xh[1] = t.x; xl[1] = t.y;
                t = split1(xv.z); xh[2] = t.x; xl[2] = t.y;
                t = split1(xv.w); xh[3] = t.x; xl[3] = t.y;
                *(short4v*)&Bh[0][xn * PB0 + 256 + d4] = xh;
                *(short4v*)&Bh[1][xn * PB0 + 256 + d4] = xl;
            }
            __syncthreads();   // S1

            // ---- MFMA: 16x16 tile mt, k-half ----
            float4v acc = {0.f, 0.f, 0.f, 0.f};
            if (mt < 2) {                       // layer 0: K=320, chunks half*5..+5
                const int k0 = half * 5 * 32;
                #pragma unroll
                for (int kc = 0; kc < 5; ++kc) {
                    const int ao = aBase + k0 + kc * 32;
                    const int bo = bBase0 + k0 + kc * 32;
                    short8 ah = *(const short8*)&Wh[0][ao];
                    short8 al = *(const short8*)&Wh[1][ao];
                    short8 bh2 = *(const short8*)&Bh[0][bo];
                    short8 bl2 = *(const short8*)&Bh[1][bo];
                    acc = MFMA16(ah, bh2, acc);
                    acc = MFMA16(ah, bl2, acc);
                    acc = MFMA16(al, bh2, acc);
                }
            } else if (half == 0) {             // layer 1, k 0..255 vs h0
                #pragma unroll
                for (int kc = 0; kc < 8; ++kc) {
                    const int ao = aBase + kc * 32;
                    const int bo = bBase0 + kc * 32;
                    short8 ah = *(const short8*)&Wh[0][ao];
                    short8 al = *(const short8*)&Wh[1][ao];
                    short8 bh2 = *(const short8*)&Bh[0][bo];
                    short8 bl2 = *(const short8*)&Bh[1][bo];
                    acc = MFMA16(ah, bh2, acc);
                    acc = MFMA16(ah, bl2, acc);
                    acc = MFMA16(al, bh2, acc);
                }
            } else {                            // layer 1, k 256..511 vs h1
                #pragma unroll
                for (int kc = 0; kc < 8; ++kc) {
                    const int ao = aBase + 256 + kc * 32;
                    const int bo = bBase1 + kc * 32;
                    short8 ah = *(const short8*)&Wh[0][ao];
                    short8 al = *(const short8*)&Wh[1][ao];
                    short8 bh2 = *(const short8*)&Bh[0][bo];
                    short8 bl2 = *(const short8*)&Bh[1][bo];
                    acc = MFMA16(ah, bh2, acc);
                    acc = MFMA16(ah, bl2, acc);
                    acc = MFMA16(al, bh2, acc);
                }
            }

            // ---- k-half combine + zf scatter ----
            if (half) *(float4v*)&zpart[mt][lane][0] = acc;
            __syncthreads();   // S2
            if (!half) {
                acc += *(const float4v*)&zpart[mt][lane][0];
                #pragma unroll
                for (int r = 0; r < 4; ++r)
                    zf[16 * mt + quad * 4 + r][n16] = acc[r];
            }
            __syncthreads();   // S3

            // ---- cell update ----
            if (tid < 256) {
                const bool active = ul ? (s >= 1) : (s < Tsz);
                if (active) {
                    const int mb = ul * 32 + ucc;
                    float z0 = zf[mb +  0][ub] + ubias[0];
                    float z1 = zf[mb +  8][ub] + ubias[1];
                    float z2 = zf[mb + 16][ub] + ubias[2];
                    float z3 = zf[mb + 24][ub] + ubias[3];
                    float ii = sigm(z0), ff = sigm(z1);
                    float gg = tanh_fast(z2), oo = sigm(z3);
                    if (ul) {
                        float c = ff * c1[p] + ii * gg; c1[p] = c;
                        float h = oo * tanh_fast(c);
                        h1last[p] = h;
                        STOREX(&h1buf[((size_t)(((s + 1) & 1) * 256) + bbase + ub) * 256 + ucol], h);
                    } else {
                        float c = ff * c0[p] + ii * gg; c0[p] = c;
                        STOREX(&h0buf[((size_t)((s & 1) * 256) + bbase + ub) * 256 + ucol],
                               oo * tanh_fast(c));
                    }
                }
            }
            // safe: next stage rewrites Bh only after S1; zpart/zf rewritten after S2.
        }

        // ---- group barrier: counter + broadcast epoch flag, no fences ----
        // __syncthreads drains each wave's vmcnt -> device-scope h stores are globally
        // visible before the arrival RMW (release without wbl2).
        __syncthreads();
        if (tid == 0) {
            const unsigned tgt = 32u * (unsigned)(s + 1);
            unsigned old = __hip_atomic_fetch_add(&syn[bs * 256], 1u,
                                                  __ATOMIC_RELAXED, __HIP_MEMORY_SCOPE_AGENT);
            if (old == tgt - 1u) {
                STOREX(&syn[2048 + bs * 256], (unsigned)(s + 1));
            } else {
                while (LOADX(&syn[2048 + bs * 256]) < (unsigned)(s + 1))
                    __builtin_amdgcn_s_sleep(1);
            }
        }
        __syncthreads();
    }

    // ---- epilogue ----
    if (tid >= 128 && tid < 256) {
        const float wf = Wf[ucol];
        atomicAdd(&out[bs * 32 + ub],      h1last[0] * wf);
        atomicAdd(&out[bs * 32 + 16 + ub], h1last[1] * wf);
    }
}

extern "C" void kernel_launch(void* const* d_in, const int* in_sizes, int n_in,
                              void* d_out, int out_size, void* d_ws, size_t ws_size,
                              hipStream_t stream) {
    const float* x    = (const float*)d_in[0];
    const float* Wih0 = (const float*)d_in[1];
    const float* Whh0 = (const float*)d_in[2];
    const float* bih0 = (const float*)d_in[3];
    const float* bhh0 = (const float*)d_in[4];
    const float* Wih1 = (const float*)d_in[5];
    const float* Whh1 = (const float*)d_in[6];
    const float* bih1 = (const float*)d_in[7];
    const float* bhh1 = (const float*)d_in[8];
    const float* Wf   = (const float*)d_in[9];
    const float* bf   = (const float*)d_in[10];
    float* out = (float*)d_out;
    float* ws  = (float*)d_ws;   // 1 MB h buffers + 16 KB sync area

    void* args[] = {
        (void*)&x, (void*)&Wih0, (void*)&Whh0, (void*)&bih0, (void*)&bhh0,
        (void*)&Wih1, (void*)&Whh1, (void*)&bih1, (void*)&bhh1,
        (void*)&Wf, (void*)&bf, (void*)&out, (void*)&ws
    };
    hipLaunchCooperativeKernel((void*)lstm2_mfma, dim3(NBLK), dim3(NTHR),
                               args, 0, stream);
}

// Round 8
// 6072.306 us; speedup vs baseline: 1.8458x; 1.1784x over previous
//
#include <hip/hip_runtime.h>
#include <hip/hip_cooperative_groups.h>
#include <math.h>

namespace cg = cooperative_groups;

#define Tsz 512
#define NBLK 256
#define NTHR 512

// LDS pitches (shorts): dword pitch ≡ 4 (mod 32) AND 16B-aligned — empirical optimum
// for the MFMA fragment b128 pattern (R5: 2.35e8 conflicts vs R6 odd-dw: 4.37e8,
// R7 ≡0: 1.076e9). Bank-group spreads as 4*(row+quad) mod 32.
#define PA0 328   // L0 A rows (K=320 used)   164 dw
#define PA1 520   // L1 A rows (K=512 used)   260 dw
#define PB0 328   // B h0|x rows (320 used)   164 dw
#define PB1 264   // B h1 rows  (256 used)    132 dw
#define A1B 10496 // 32*PA0
#define B1B 5248  // 16*PB0

typedef short short8  __attribute__((ext_vector_type(8)));
typedef short short4v __attribute__((ext_vector_type(4)));
typedef float float4v __attribute__((ext_vector_type(4)));

#define MFMA16(a, b, c) __builtin_amdgcn_mfma_f32_16x16x32_bf16((a), (b), (c), 0, 0, 0)
#define LOADX(p) __hip_atomic_load((p), __ATOMIC_RELAXED, __HIP_MEMORY_SCOPE_AGENT)
#define STOREX(p, v) __hip_atomic_store((p), (v), __ATOMIC_RELAXED, __HIP_MEMORY_SCOPE_AGENT)

__device__ __forceinline__ float sigm(float x) { return 1.0f / (1.0f + __expf(-x)); }
__device__ __forceinline__ float tanh_fast(float x) { return 2.0f / (1.0f + __expf(-2.0f * x)) - 1.0f; }

// fp32 -> bf16 hi (x) + bf16 lo (y), RNE both
__device__ __forceinline__ short2 split1(float f) {
    unsigned u = __float_as_uint(f);
    unsigned r = u + 0x7FFFu + ((u >> 16) & 1u);
    short h = (short)(r >> 16);
    float hf = __uint_as_float(r & 0xFFFF0000u);
    float d  = f - hf;
    unsigned u2 = __float_as_uint(d);
    unsigned r2 = u2 + 0x7FFFu + ((u2 >> 16) & 1u);
    return make_short2(h, (short)(r2 >> 16));
}

// Weight-stationary 2-layer LSTM, bf16-split-3 MFMA, pipelined sub-group barriers.
// 256 blocks = 32 row-slices (8 cols) x 8 batch-slices. Each bs-group's 32 batches
// split into sub-groups A (16) and B (16) with independent counter+flag barriers;
// A's exchange latency hides behind B's compute phase and vice versa.
__global__ __launch_bounds__(NTHR, 1)
void lstm2_mfma(const float* __restrict__ x,
                const float* __restrict__ Wih0, const float* __restrict__ Whh0,
                const float* __restrict__ bih0, const float* __restrict__ bhh0,
                const float* __restrict__ Wih1, const float* __restrict__ Whh1,
                const float* __restrict__ bih1, const float* __restrict__ bhh1,
                const float* __restrict__ Wf,   const float* __restrict__ bf,
                float* __restrict__ out, float* __restrict__ ws)
{
    cg::grid_group grid = cg::this_grid();
    const int tid = threadIdx.x;
    const int rs  = blockIdx.x >> 3;
    const int bs  = blockIdx.x & 7;

    __shared__ short Wh[2][27136];          // 108.5 KB
    __shared__ short Bh[2][9472];           // 37.9 KB
    __shared__ float zf2[2][64][17];        // 8.7 KB: [k-half][row][batch]

    float* h0buf = ws;                          // [2 parity][256 batch][256 col]
    float* h1buf = ws + 2 * 256 * 256;
    unsigned* syn = (unsigned*)(ws + 4 * 256 * 256);
    // cntA: syn[bs*256], flagA: syn[2048+bs*256], cntB: syn[4096+bs*256],
    // flagB: syn[6144+bs*256]  (1KB apart each)

    // ---- init ----
    for (int i = blockIdx.x * NTHR + tid; i < 4 * 256 * 256; i += NBLK * NTHR) ws[i] = 0.f;
    if (rs == 0 && tid < 4) syn[tid * 2048 + bs * 256] = 0u;
    if (rs == 0 && tid < 32) out[bs * 32 + tid] = bf[0];

    // ---- one-time weight stage: fp32 -> hi/lo bf16 planes ----
    for (int m = 0; m < 64; ++m) {
        const int L = m >> 5, wr = m & 31, g = wr >> 3, cc = wr & 7;
        const size_t grow = (size_t)(g * 256 + rs * 8 + cc);
        const int klen = L ? 512 : 320;
        const int base = L ? A1B + (m - 32) * PA1 : m * PA0;
        for (int k = tid; k < klen; k += NTHR) {
            float w;
            if (!L) w = (k < 256) ? Whh0[grow * 256 + k] : Wih0[grow * 64 + (k - 256)];
            else    w = (k < 256) ? Wih1[grow * 256 + k] : Whh1[grow * 256 + (k - 256)];
            short2 hl = split1(w);
            Wh[0][base + k] = hl.x; Wh[1][base + k] = hl.y;
        }
    }

    // ---- mfma lane decode ----
    const int wv = tid >> 6, lane = tid & 63;
    const int mt = wv & 3, half = wv >> 2;
    const int quad = lane >> 4, n16 = lane & 15;
    const int rowA = 16 * mt + n16;
    const int aBase = (rowA < 32 ? rowA * PA0 : A1B + (rowA - 32) * PA1) + quad * 8;
    const int bBase0 = n16 * PB0 + quad * 8;
    const int bBase1 = B1B + n16 * PB1 + quad * 8;

    // ---- updater decode (tid < 256) ----
    const int ul = tid >> 7, ucc = tid & 7, ub = (tid >> 3) & 15;
    const int ucol = rs * 8 + ucc;
    float ubias[4];
    if (tid < 256) {
        const float* bi = ul ? bih1 : bih0;
        const float* bh = ul ? bhh1 : bhh0;
        #pragma unroll
        for (int g = 0; g < 4; ++g) ubias[g] = bi[g * 256 + ucol] + bh[g * 256 + ucol];
    }
    float c0[2] = {0.f, 0.f}, c1[2] = {0.f, 0.f}, h1last[2] = {0.f, 0.f};

    grid.sync();   // init + weights visible device-wide

    for (int s = 0; s <= Tsz; ++s) {
        const int rp = (s + 1) & 1;   // parity of h0[s-1]
        const int rq = s & 1;         // parity of h1[s-2]
        #pragma unroll
        for (int sub = 0; sub < 2; ++sub) {
            const int bbase = bs * 32 + sub * 16;

            // ---- stage h0[s-1], h1[s-2], x[.,s,.] -> hi/lo bf16 B-planes ----
            {
                const int sn = tid >> 5, sk = (tid & 31) * 8;
                const float* p0 = &h0buf[((size_t)(rp * 256) + bbase + sn) * 256 + sk];
                const float* p1 = &h1buf[((size_t)(rq * 256) + bbase + sn) * 256 + sk];
                float v0[8], v1[8];
                #pragma unroll
                for (int i = 0; i < 8; ++i) v0[i] = LOADX(p0 + i);
                #pragma unroll
                for (int i = 0; i < 8; ++i) v1[i] = LOADX(p1 + i);
                short8 hi, lo;
                #pragma unroll
                for (int i = 0; i < 8; ++i) {
                    short2 t = split1(v0[i]); hi[i] = t.x; lo[i] = t.y;
                }
                *(short8*)&Bh[0][sn * PB0 + sk] = hi;
                *(short8*)&Bh[1][sn * PB0 + sk] = lo;
                #pragma unroll
                for (int i = 0; i < 8; ++i) {
                    short2 t = split1(v1[i]); hi[i] = t.x; lo[i] = t.y;
                }
                *(short8*)&Bh[0][B1B + sn * PB1 + sk] = hi;
                *(short8*)&Bh[1][B1B + sn * PB1 + sk] = lo;
            }
            if (s < Tsz && tid < 256) {
                const int xn = tid >> 4, d4 = (tid & 15) * 4;
                float4 xv = *(const float4*)&x[((size_t)(bbase + xn) * Tsz + s) * 64 + d4];
                short4v xh, xl;
                short2 t;
                t = split1(xv.x); xh[0] = t.x; xl[0] = t.y;
                t = split1(xv.y); xh[1] = t.x; xl[1] = t.y;
                t = split1(xv.z); xh[2] = t.x; xl[2] = t.y;
                t = split1(xv.w); xh[3] = t.x; xl[3] = t.y;
                *(short4v*)&Bh[0][xn * PB0 + 256 + d4] = xh;
                *(short4v*)&Bh[1][xn * PB0 + 256 + d4] = xl;
            }
            __syncthreads();   // S1: Bh staged

            // ---- MFMA: 16x16 tile mt, k-half ----
            float4v acc = {0.f, 0.f, 0.f, 0.f};
            if (mt < 2) {                       // layer 0: K=320
                const int k0 = half * 5 * 32;
                #pragma unroll
                for (int kc = 0; kc < 5; ++kc) {
                    const int ao = aBase + k0 + kc * 32;
                    const int bo = bBase0 + k0 + kc * 32;
                    short8 ah = *(const short8*)&Wh[0][ao];
                    short8 al = *(const short8*)&Wh[1][ao];
                    short8 bh2 = *(const short8*)&Bh[0][bo];
                    short8 bl2 = *(const short8*)&Bh[1][bo];
                    acc = MFMA16(ah, bh2, acc);
                    acc = MFMA16(ah, bl2, acc);
                    acc = MFMA16(al, bh2, acc);
                }
            } else if (half == 0) {             // layer 1, k 0..255 vs h0
                #pragma unroll
                for (int kc = 0; kc < 8; ++kc) {
                    const int ao = aBase + kc * 32;
                    const int bo = bBase0 + kc * 32;
                    short8 ah = *(const short8*)&Wh[0][ao];
                    short8 al = *(const short8*)&Wh[1][ao];
                    short8 bh2 = *(const short8*)&Bh[0][bo];
                    short8 bl2 = *(const short8*)&Bh[1][bo];
                    acc = MFMA16(ah, bh2, acc);
                    acc = MFMA16(ah, bl2, acc);
                    acc = MFMA16(al, bh2, acc);
                }
            } else {                            // layer 1, k 256..511 vs h1
                #pragma unroll
                for (int kc = 0; kc < 8; ++kc) {
                    const int ao = aBase + 256 + kc * 32;
                    const int bo = bBase1 + kc * 32;
                    short8 ah = *(const short8*)&Wh[0][ao];
                    short8 al = *(const short8*)&Wh[1][ao];
                    short8 bh2 = *(const short8*)&Bh[0][bo];
                    short8 bl2 = *(const short8*)&Bh[1][bo];
                    acc = MFMA16(ah, bh2, acc);
                    acc = MFMA16(ah, bl2, acc);
                    acc = MFMA16(al, bh2, acc);
                }
            }

            // ---- scatter both k-half partials; updater sums the planes ----
            #pragma unroll
            for (int r = 0; r < 4; ++r)
                zf2[half][16 * mt + quad * 4 + r][n16] = acc[r];
            __syncthreads();   // S2: zf2 complete

            // ---- cell update ----
            if (tid < 256) {
                const bool active = ul ? (s >= 1) : (s < Tsz);
                if (active) {
                    const int mb = ul * 32 + ucc;
                    float z0 = zf2[0][mb +  0][ub] + zf2[1][mb +  0][ub] + ubias[0];
                    float z1 = zf2[0][mb +  8][ub] + zf2[1][mb +  8][ub] + ubias[1];
                    float z2 = zf2[0][mb + 16][ub] + zf2[1][mb + 16][ub] + ubias[2];
                    float z3 = zf2[0][mb + 24][ub] + zf2[1][mb + 24][ub] + ubias[3];
                    float ii = sigm(z0), ff = sigm(z1);
                    float gg = tanh_fast(z2), oo = sigm(z3);
                    if (ul) {
                        float c = ff * c1[sub] + ii * gg; c1[sub] = c;
                        float h = oo * tanh_fast(c);
                        h1last[sub] = h;
                        STOREX(&h1buf[((size_t)(((s + 1) & 1) * 256) + bbase + ub) * 256 + ucol], h);
                    } else {
                        float c = ff * c0[sub] + ii * gg; c0[sub] = c;
                        STOREX(&h0buf[((size_t)((s & 1) * 256) + bbase + ub) * 256 + ucol],
                               oo * tanh_fast(c));
                    }
                }
            }

            // ---- drain stores, arrive(this sub, s), wait(other sub) ----
            // __syncthreads drains each wave's vmcnt -> sc1 stores globally visible.
            __syncthreads();
            if (tid == 0) {
                const unsigned arrC = sub ? 4096u : 0u;
                const unsigned arrF = sub ? 6144u : 2048u;
                unsigned old = __hip_atomic_fetch_add(&syn[arrC + bs * 256], 1u,
                                                      __ATOMIC_RELAXED, __HIP_MEMORY_SCOPE_AGENT);
                if (old == 32u * (unsigned)(s + 1) - 1u)
                    STOREX(&syn[arrF + bs * 256], (unsigned)(s + 1));
                // wait for the OTHER sub-group's h to be ready for its next stage:
                // sub=0 phase waits B>=s (B stages step s next); sub=1 waits A>=s+1.
                const unsigned wantS = sub ? (unsigned)(s + 1) : (unsigned)s;
                const unsigned wF = sub ? 2048u : 6144u;
                if (wantS <= (unsigned)Tsz) {
                    while (LOADX(&syn[wF + bs * 256]) < wantS)
                        __builtin_amdgcn_s_sleep(1);
                }
            }
            __syncthreads();
        }
    }

    // ---- epilogue ----
    if (tid >= 128 && tid < 256) {
        const float wf = Wf[ucol];
        atomicAdd(&out[bs * 32 + ub],      h1last[0] * wf);
        atomicAdd(&out[bs * 32 + 16 + ub], h1last[1] * wf);
    }
}

extern "C" void kernel_launch(void* const* d_in, const int* in_sizes, int n_in,
                              void* d_out, int out_size, void* d_ws, size_t ws_size,
                              hipStream_t stream) {
    const float* x    = (const float*)d_in[0];
    const float* Wih0 = (const float*)d_in[1];
    const float* Whh0 = (const float*)d_in[2];
    const float* bih0 = (const float*)d_in[3];
    const float* bhh0 = (const float*)d_in[4];
    const float* Wih1 = (const float*)d_in[5];
    const float* Whh1 = (const float*)d_in[6];
    const float* bih1 = (const float*)d_in[7];
    const float* bhh1 = (const float*)d_in[8];
    const float* Wf   = (const float*)d_in[9];
    const float* bf   = (const float*)d_in[10];
    float* out = (float*)d_out;
    float* ws  = (float*)d_ws;   // 1 MB h buffers + 32 KB sync area

    void* args[] = {
        (void*)&x, (void*)&Wih0, (void*)&Whh0, (void*)&bih0, (void*)&bhh0,
        (void*)&Wih1, (void*)&Whh1, (void*)&bih1, (void*)&bhh1,
        (void*)&Wf, (void*)&bf, (void*)&out, (void*)&ws
    };
    hipLaunchCooperativeKernel((void*)lstm2_mfma, dim3(NBLK), dim3(NTHR),
                               args, 0, stream);
}

// Round 9
// 5349.775 us; speedup vs baseline: 2.0951x; 1.1351x over previous
//
#include <hip/hip_runtime.h>
#include <hip/hip_cooperative_groups.h>
#include <math.h>

namespace cg = cooperative_groups;

#define Tsz 512
#define NBLK 256
#define NTHR 512

// LDS pitches (shorts): dword pitch ≡ 4 (mod 32) AND 16B-aligned — empirical optimum
// for the MFMA fragment b128 pattern (R5: 2.35e8 conflicts; odd-dw: 4.37e8; ≡0: 1.08e9).
#define PB0 328   // B h0|x rows (320 used)   164 dw
#define PB1 264   // B h1 rows  (256 used)    132 dw
#define B1B 5248  // 16*PB0

typedef short short8  __attribute__((ext_vector_type(8)));
typedef short short4v __attribute__((ext_vector_type(4)));
typedef float float4v __attribute__((ext_vector_type(4)));

#define MFMA16(a, b, c) __builtin_amdgcn_mfma_f32_16x16x32_bf16((a), (b), (c), 0, 0, 0)
#define LOADX(p) __hip_atomic_load((p), __ATOMIC_RELAXED, __HIP_MEMORY_SCOPE_AGENT)
#define STOREX(p, v) __hip_atomic_store((p), (v), __ATOMIC_RELAXED, __HIP_MEMORY_SCOPE_AGENT)

__device__ __forceinline__ float sigm(float x) { return 1.0f / (1.0f + __expf(-x)); }
__device__ __forceinline__ float tanh_fast(float x) { return 2.0f / (1.0f + __expf(-2.0f * x)) - 1.0f; }

// fp32 -> bf16 hi (x) + bf16 lo (y), RNE both
__device__ __forceinline__ short2 split1(float f) {
    unsigned u = __float_as_uint(f);
    unsigned r = u + 0x7FFFu + ((u >> 16) & 1u);
    short h = (short)(r >> 16);
    float hf = __uint_as_float(r & 0xFFFF0000u);
    float d  = f - hf;
    unsigned u2 = __float_as_uint(d);
    unsigned r2 = u2 + 0x7FFFu + ((u2 >> 16) & 1u);
    return make_short2(h, (short)(r2 >> 16));
}

// Weight-stationary 2-layer LSTM, bf16-split-3 MFMA.
// R9: weight A-fragments live in REGISTERS (no Wh LDS); h exchanged as packed
// (hi16|lo16) uints, v_perm unpack; x prefetched one superstep ahead; all-wave
// flag polling. Same 32 rs x 8 bs grid, A/B sub-group pipelined barriers.
__global__ __launch_bounds__(NTHR, 1)
void lstm2_mfma(const float* __restrict__ x,
                const float* __restrict__ Wih0, const float* __restrict__ Whh0,
                const float* __restrict__ bih0, const float* __restrict__ bhh0,
                const float* __restrict__ Wih1, const float* __restrict__ Whh1,
                const float* __restrict__ bih1, const float* __restrict__ bhh1,
                const float* __restrict__ Wf,   const float* __restrict__ bf,
                float* __restrict__ out, float* __restrict__ ws)
{
    cg::grid_group grid = cg::this_grid();
    const int tid = threadIdx.x;
    const int rs  = blockIdx.x >> 3;
    const int bs  = blockIdx.x & 7;

    __shared__ short Bh[2][9472];           // 37.9 KB (h0|x: 16*PB0, h1: 16*PB1)
    __shared__ float zf2[2][64][17];        // 8.7 KB

    unsigned* h0u = (unsigned*)ws;              // [2 parity][256 batch][256 col] packed
    unsigned* h1u = (unsigned*)ws + 2 * 256 * 256;
    unsigned* syn = (unsigned*)ws + 4 * 256 * 256;
    // cntA syn[bs*256], flagA syn[2048+bs*256], cntB syn[4096+..], flagB syn[6144+..]

    // ---- init ----
    for (int i = blockIdx.x * NTHR + tid; i < 4 * 256 * 256; i += NBLK * NTHR)
        ((unsigned*)ws)[i] = 0u;
    if (rs == 0 && tid < 4) syn[tid * 2048 + bs * 256] = 0u;
    if (rs == 0 && tid < 32) out[bs * 32 + tid] = bf[0];

    // ---- mfma lane decode ----
    const int wv = tid >> 6, lane = tid & 63;
    const int mt = wv & 3, half = wv >> 2;
    const int quad = lane >> 4, n16 = lane & 15;
    const int rowA = 16 * mt + n16;
    const int bBase0 = n16 * PB0 + quad * 8;
    const int bBase1 = B1B + n16 * PB1 + quad * 8;

    // ---- weight A-fragments -> registers (no LDS) ----
    short8 wfh[8], wfl[8];
    {
        const int r = (rowA < 32) ? rowA : rowA - 32;
        const size_t grow = (size_t)((r >> 3) * 256 + rs * 8 + (r & 7));
        const int nkc = (mt < 2) ? 5 : 8;
        #pragma unroll
        for (int kc = 0; kc < 8; ++kc) {
            if (kc < nkc) {
                const float* src;
                if (rowA < 32) {                 // L0: K=320 (h0 | x)
                    int k = half * 160 + kc * 32 + quad * 8;
                    src = (k < 256) ? &Whh0[grow * 256 + k] : &Wih0[grow * 64 + (k - 256)];
                } else {                          // L1: half0 = Wih1, half1 = Whh1
                    int k = kc * 32 + quad * 8;
                    src = (half == 0) ? &Wih1[grow * 256 + k] : &Whh1[grow * 256 + k];
                }
                float4 f0 = *(const float4*)src;
                float4 f1 = *(const float4*)(src + 4);
                short8 hi, lo; short2 t;
                t = split1(f0.x); hi[0] = t.x; lo[0] = t.y;
                t = split1(f0.y); hi[1] = t.x; lo[1] = t.y;
                t = split1(f0.z); hi[2] = t.x; lo[2] = t.y;
                t = split1(f0.w); hi[3] = t.x; lo[3] = t.y;
                t = split1(f1.x); hi[4] = t.x; lo[4] = t.y;
                t = split1(f1.y); hi[5] = t.x; lo[5] = t.y;
                t = split1(f1.z); hi[6] = t.x; lo[6] = t.y;
                t = split1(f1.w); hi[7] = t.x; lo[7] = t.y;
                wfh[kc] = hi; wfl[kc] = lo;
            }
        }
    }

    // ---- updater decode (tid < 256) ----
    const int ul = tid >> 7, ucc = tid & 7, ub = (tid >> 3) & 15;
    const int ucol = rs * 8 + ucc;
    float ubias[4];
    if (tid < 256) {
        const float* bi = ul ? bih1 : bih0;
        const float* bh = ul ? bhh1 : bhh0;
        #pragma unroll
        for (int g = 0; g < 4; ++g) ubias[g] = bi[g * 256 + ucol] + bh[g * 256 + ucol];
    }
    float c0[2] = {0.f, 0.f}, c1[2] = {0.f, 0.f}, h1last[2] = {0.f, 0.f};

    // staging decode
    const int sn = tid >> 5, sk = (tid & 31) * 8;
    const int xn = tid >> 4, xd4 = (tid & 15) * 4;

    grid.sync();   // init visible device-wide

    // ---- x prefetch for s=0 (both sub-groups) ----
    float4 xpre[2];
    if (tid < 256) {
        #pragma unroll
        for (int sub = 0; sub < 2; ++sub)
            xpre[sub] = *(const float4*)&x[((size_t)(bs * 32 + sub * 16 + xn) * Tsz + 0) * 64 + xd4];
    }

    for (int s = 0; s <= Tsz; ++s) {
        const int rp = (s + 1) & 1;   // parity of h0[s-1]
        const int rq = s & 1;         // parity of h1[s-2]
        #pragma unroll
        for (int sub = 0; sub < 2; ++sub) {
            const int bbase = bs * 32 + sub * 16;

            // ---- stage h0[s-1], h1[s-2] (packed-uint load + v_perm unpack), x ----
            {
                const unsigned* q0 = &h0u[((size_t)(rp * 256) + bbase + sn) * 256 + sk];
                const unsigned* q1 = &h1u[((size_t)(rq * 256) + bbase + sn) * 256 + sk];
                unsigned a[8], b[8];
                #pragma unroll
                for (int i = 0; i < 8; ++i) a[i] = LOADX(q0 + i);
                #pragma unroll
                for (int i = 0; i < 8; ++i) b[i] = LOADX(q1 + i);
                uint4 hi4, lo4;
                hi4.x = __builtin_amdgcn_perm(a[1], a[0], 0x07060302u);
                hi4.y = __builtin_amdgcn_perm(a[3], a[2], 0x07060302u);
                hi4.z = __builtin_amdgcn_perm(a[5], a[4], 0x07060302u);
                hi4.w = __builtin_amdgcn_perm(a[7], a[6], 0x07060302u);
                lo4.x = __builtin_amdgcn_perm(a[1], a[0], 0x05040100u);
                lo4.y = __builtin_amdgcn_perm(a[3], a[2], 0x05040100u);
                lo4.z = __builtin_amdgcn_perm(a[5], a[4], 0x05040100u);
                lo4.w = __builtin_amdgcn_perm(a[7], a[6], 0x05040100u);
                *(uint4*)&Bh[0][sn * PB0 + sk] = hi4;
                *(uint4*)&Bh[1][sn * PB0 + sk] = lo4;
                hi4.x = __builtin_amdgcn_perm(b[1], b[0], 0x07060302u);
                hi4.y = __builtin_amdgcn_perm(b[3], b[2], 0x07060302u);
                hi4.z = __builtin_amdgcn_perm(b[5], b[4], 0x07060302u);
                hi4.w = __builtin_amdgcn_perm(b[7], b[6], 0x07060302u);
                lo4.x = __builtin_amdgcn_perm(b[1], b[0], 0x05040100u);
                lo4.y = __builtin_amdgcn_perm(b[3], b[2], 0x05040100u);
                lo4.z = __builtin_amdgcn_perm(b[5], b[4], 0x05040100u);
                lo4.w = __builtin_amdgcn_perm(b[7], b[6], 0x05040100u);
                *(uint4*)&Bh[0][B1B + sn * PB1 + sk] = hi4;
                *(uint4*)&Bh[1][B1B + sn * PB1 + sk] = lo4;
            }
            if (s < Tsz && tid < 256) {
                float4 xv = xpre[sub];
                short4v xh, xl; short2 t;
                t = split1(xv.x); xh[0] = t.x; xl[0] = t.y;
                t = split1(xv.y); xh[1] = t.x; xl[1] = t.y;
                t = split1(xv.z); xh[2] = t.x; xl[2] = t.y;
                t = split1(xv.w); xh[3] = t.x; xl[3] = t.y;
                *(short4v*)&Bh[0][xn * PB0 + 256 + xd4] = xh;
                *(short4v*)&Bh[1][xn * PB0 + 256 + xd4] = xl;
            }
            __syncthreads();   // S1: Bh staged

            // x prefetch for next superstep (drains at S2, used next superstep)
            if (tid < 256 && s + 1 < Tsz)
                xpre[sub] = *(const float4*)&x[((size_t)(bbase + xn) * Tsz + (s + 1)) * 64 + xd4];

            // ---- MFMA from register A-frags + LDS B-frags ----
            float4v acc = {0.f, 0.f, 0.f, 0.f};
            if (mt < 2) {                       // layer 0: K=320
                const int k0 = half * 5 * 32;
                #pragma unroll
                for (int kc = 0; kc < 5; ++kc) {
                    const int bo = bBase0 + k0 + kc * 32;
                    short8 bh2 = *(const short8*)&Bh[0][bo];
                    short8 bl2 = *(const short8*)&Bh[1][bo];
                    acc = MFMA16(wfh[kc], bh2, acc);
                    acc = MFMA16(wfh[kc], bl2, acc);
                    acc = MFMA16(wfl[kc], bh2, acc);
                }
            } else if (half == 0) {             // layer 1 vs h0
                #pragma unroll
                for (int kc = 0; kc < 8; ++kc) {
                    const int bo = bBase0 + kc * 32;
                    short8 bh2 = *(const short8*)&Bh[0][bo];
                    short8 bl2 = *(const short8*)&Bh[1][bo];
                    acc = MFMA16(wfh[kc], bh2, acc);
                    acc = MFMA16(wfh[kc], bl2, acc);
                    acc = MFMA16(wfl[kc], bh2, acc);
                }
            } else {                            // layer 1 vs h1
                #pragma unroll
                for (int kc = 0; kc < 8; ++kc) {
                    const int bo = bBase1 + kc * 32;
                    short8 bh2 = *(const short8*)&Bh[0][bo];
                    short8 bl2 = *(const short8*)&Bh[1][bo];
                    acc = MFMA16(wfh[kc], bh2, acc);
                    acc = MFMA16(wfh[kc], bl2, acc);
                    acc = MFMA16(wfl[kc], bh2, acc);
                }
            }

            // ---- scatter both k-half partials; updater sums planes ----
            #pragma unroll
            for (int r = 0; r < 4; ++r)
                zf2[half][16 * mt + quad * 4 + r][n16] = acc[r];
            __syncthreads();   // S2

            // ---- cell update (split+pack once at producer) ----
            if (tid < 256) {
                const bool active = ul ? (s >= 1) : (s < Tsz);
                if (active) {
                    const int mb = ul * 32 + ucc;
                    float z0 = zf2[0][mb +  0][ub] + zf2[1][mb +  0][ub] + ubias[0];
                    float z1 = zf2[0][mb +  8][ub] + zf2[1][mb +  8][ub] + ubias[1];
                    float z2 = zf2[0][mb + 16][ub] + zf2[1][mb + 16][ub] + ubias[2];
                    float z3 = zf2[0][mb + 24][ub] + zf2[1][mb + 24][ub] + ubias[3];
                    float ii = sigm(z0), ff = sigm(z1);
                    float gg = tanh_fast(z2), oo = sigm(z3);
                    float hval;
                    if (ul) {
                        float c = ff * c1[sub] + ii * gg; c1[sub] = c;
                        hval = oo * tanh_fast(c);
                        h1last[sub] = hval;
                        short2 hl = split1(hval);
                        unsigned pk = ((unsigned)(unsigned short)hl.x << 16) |
                                      (unsigned)(unsigned short)hl.y;
                        STOREX(&h1u[((size_t)(((s + 1) & 1) * 256) + bbase + ub) * 256 + ucol], pk);
                    } else {
                        float c = ff * c0[sub] + ii * gg; c0[sub] = c;
                        hval = oo * tanh_fast(c);
                        short2 hl = split1(hval);
                        unsigned pk = ((unsigned)(unsigned short)hl.x << 16) |
                                      (unsigned)(unsigned short)hl.y;
                        STOREX(&h0u[((size_t)((s & 1) * 256) + bbase + ub) * 256 + ucol], pk);
                    }
                }
            }

            // ---- drain stores (S3), arrive, all-wave poll ----
            __syncthreads();   // S3: all Bh/zf2 reads done + h stores drained at barrier
            if (tid == 0) {
                const unsigned arrC = sub ? 4096u : 0u;
                const unsigned arrF = sub ? 6144u : 2048u;
                unsigned old = __hip_atomic_fetch_add(&syn[arrC + bs * 256], 1u,
                                                      __ATOMIC_RELAXED, __HIP_MEMORY_SCOPE_AGENT);
                if (old == 32u * (unsigned)(s + 1) - 1u)
                    STOREX(&syn[arrF + bs * 256], (unsigned)(s + 1));
            }
            // wait for the OTHER sub-group (guards the immediately-following pass);
            // every wave polls independently — no trailing __syncthreads.
            {
                const unsigned wantS = sub ? (unsigned)(s + 1) : (unsigned)s;
                const unsigned wF = sub ? 2048u : 6144u;
                if (wantS <= (unsigned)Tsz) {
                    while (LOADX(&syn[wF + bs * 256]) < wantS)
                        __builtin_amdgcn_s_sleep(1);
                }
            }
        }
    }

    // ---- epilogue ----
    if (tid >= 128 && tid < 256) {
        const float wf = Wf[ucol];
        atomicAdd(&out[bs * 32 + ub],      h1last[0] * wf);
        atomicAdd(&out[bs * 32 + 16 + ub], h1last[1] * wf);
    }
}

extern "C" void kernel_launch(void* const* d_in, const int* in_sizes, int n_in,
                              void* d_out, int out_size, void* d_ws, size_t ws_size,
                              hipStream_t stream) {
    const float* x    = (const float*)d_in[0];
    const float* Wih0 = (const float*)d_in[1];
    const float* Whh0 = (const float*)d_in[2];
    const float* bih0 = (const float*)d_in[3];
    const float* bhh0 = (const float*)d_in[4];
    const float* Wih1 = (const float*)d_in[5];
    const float* Whh1 = (const float*)d_in[6];
    const float* bih1 = (const float*)d_in[7];
    const float* bhh1 = (const float*)d_in[8];
    const float* Wf   = (const float*)d_in[9];
    const float* bf   = (const float*)d_in[10];
    float* out = (float*)d_out;
    float* ws  = (float*)d_ws;   // 1 MB packed h buffers + 32 KB sync area

    void* args[] = {
        (void*)&x, (void*)&Wih0, (void*)&Whh0, (void*)&bih0, (void*)&bhh0,
        (void*)&Wih1, (void*)&Whh1, (void*)&bih1, (void*)&bhh1,
        (void*)&Wf, (void*)&bf, (void*)&out, (void*)&ws
    };
    hipLaunchCooperativeKernel((void*)lstm2_mfma, dim3(NBLK), dim3(NTHR),
                               args, 0, stream);
}

// Round 10
// 3441.468 us; speedup vs baseline: 3.2569x; 1.5545x over previous
//
#include <hip/hip_runtime.h>
#include <hip/hip_cooperative_groups.h>
#include <math.h>

namespace cg = cooperative_groups;

#define Tsz 512
#define NBLK 256
#define NTHR 512

// LDS pitches (shorts): dword pitch ≡ 4 (mod 32), 16B-aligned — empirical optimum for
// the MFMA fragment b128 pattern (R5/R8: 2.4e8 conflicts; odd-dw: 4.4e8; ≡0: 1.1e9).
#define PB0 328   // B h0|x rows (320 used)  164 dw
#define PB1 264   // B h1 rows  (256 used)   132 dw
#define B1B 5248  // 16*PB0

typedef short short8  __attribute__((ext_vector_type(8)));
typedef short short4v __attribute__((ext_vector_type(4)));
typedef float float4v __attribute__((ext_vector_type(4)));

#define MFMA16(a, b, c) __builtin_amdgcn_mfma_f32_16x16x32_bf16((a), (b), (c), 0, 0, 0)
#define LOADX(p) __hip_atomic_load((p), __ATOMIC_RELAXED, __HIP_MEMORY_SCOPE_AGENT)
#define STOREX(p, v) __hip_atomic_store((p), (v), __ATOMIC_RELAXED, __HIP_MEMORY_SCOPE_AGENT)

__device__ __forceinline__ float sigm(float x) { return 1.0f / (1.0f + __expf(-x)); }
__device__ __forceinline__ float tanh_fast(float x) { return 2.0f / (1.0f + __expf(-2.0f * x)) - 1.0f; }

// fp32 -> bf16 hi (x) + bf16 lo (y), RNE both
__device__ __forceinline__ short2 split1(float f) {
    unsigned u = __float_as_uint(f);
    unsigned r = u + 0x7FFFu + ((u >> 16) & 1u);
    short h = (short)(r >> 16);
    float hf = __uint_as_float(r & 0xFFFF0000u);
    float d  = f - hf;
    unsigned u2 = __float_as_uint(d);
    unsigned r2 = u2 + 0x7FFFu + ((u2 >> 16) & 1u);
    return make_short2(h, (short)(r2 >> 16));
}

// Weight-stationary 2-layer LSTM, bf16-split-3 MFMA, ONE pass per superstep.
// 256 blocks = 16 row-slices (16 cols) x 16 batch-slices (16 batches).
// M=128 rows (L0 rows 0..63 = gate*16+col, L1 rows 64..127), N=16 batches.
// 8 waves = 8 16x16 tiles, FULL K per wave (L0: K=320 h0|x, L1: K=512 h0|h1) —
// no k-split, no partial-combine. Weight A-frags in registers. One 16-block
// barrier (counter + epoch flag, no fences) per superstep.
__global__ __launch_bounds__(NTHR, 1)
void lstm2_mfma(const float* __restrict__ x,
                const float* __restrict__ Wih0, const float* __restrict__ Whh0,
                const float* __restrict__ bih0, const float* __restrict__ bhh0,
                const float* __restrict__ Wih1, const float* __restrict__ Whh1,
                const float* __restrict__ bih1, const float* __restrict__ bhh1,
                const float* __restrict__ Wf,   const float* __restrict__ bf,
                float* __restrict__ out, float* __restrict__ ws)
{
    cg::grid_group grid = cg::this_grid();
    const int tid = threadIdx.x;
    const int rs  = blockIdx.x >> 4;   // row-slice: cols [rs*16, rs*16+16)
    const int bs  = blockIdx.x & 15;   // batch-slice: batches [bs*16, bs*16+16)
    const int bbase = bs * 16;

    __shared__ short Bh[2][9472];      // 37.9 KB (h0|x: 16*PB0, h1: 16*PB1)
    __shared__ float zf[128][17];      // 8.7 KB

    unsigned* h0u = (unsigned*)ws;             // [2 parity][256 batch][256 col] packed
    unsigned* h1u = (unsigned*)ws + 2 * 256 * 256;
    unsigned* syn = (unsigned*)ws + 4 * 256 * 256;
    // cnt: syn[bs*256], flag: syn[4096 + bs*256]  (1KB apart)

    // ---- init ----
    for (int i = blockIdx.x * NTHR + tid; i < 4 * 256 * 256; i += NBLK * NTHR)
        ((unsigned*)ws)[i] = 0u;
    if (rs == 0 && tid < 2) syn[tid * 4096 + bs * 256] = 0u;
    if (rs == 0 && tid < 16) out[bbase + tid] = bf[0];

    // ---- mfma lane decode ----
    const int w = tid >> 6, lane = tid & 63;
    const int quad = lane >> 4, n16 = lane & 15;
    const int bBase0 = n16 * PB0 + quad * 8;
    const int bBase1 = B1B + n16 * PB1 + quad * 8;

    // ---- weight A-fragments -> registers (full K per wave) ----
    // Wave w<4: L0 tile rows w*16..+16 (within-layer row r = w*16+n16).
    // Wave w>=4: L1 tile rows (w-4)*16..+16.
    short8 wfh[16], wfl[16];
    {
        const int r = (w & 3) * 16 + n16;            // within-layer row 0..63
        const int g = r >> 4, cc = r & 15;
        const size_t grow = (size_t)(g * 256 + rs * 16 + cc);
        const int nkc = (w < 4) ? 10 : 16;
        #pragma unroll
        for (int kc = 0; kc < 16; ++kc) {
            if (kc < nkc) {
                const int k = kc * 32 + quad * 8;
                const float* src;
                if (w < 4)                           // L0: k<256 -> Whh0, else Wih0
                    src = (k < 256) ? &Whh0[grow * 256 + k] : &Wih0[grow * 64 + (k - 256)];
                else                                 // L1: k<256 -> Wih1 (vs h0), else Whh1 (vs h1)
                    src = (k < 256) ? &Wih1[grow * 256 + k] : &Whh1[grow * 256 + (k - 256)];
                float4 f0 = *(const float4*)src;
                float4 f1 = *(const float4*)(src + 4);
                short8 hi, lo; short2 t;
                t = split1(f0.x); hi[0] = t.x; lo[0] = t.y;
                t = split1(f0.y); hi[1] = t.x; lo[1] = t.y;
                t = split1(f0.z); hi[2] = t.x; lo[2] = t.y;
                t = split1(f0.w); hi[3] = t.x; lo[3] = t.y;
                t = split1(f1.x); hi[4] = t.x; lo[4] = t.y;
                t = split1(f1.y); hi[5] = t.x; lo[5] = t.y;
                t = split1(f1.z); hi[6] = t.x; lo[6] = t.y;
                t = split1(f1.w); hi[7] = t.x; lo[7] = t.y;
                wfh[kc] = hi; wfl[kc] = lo;
            }
        }
    }

    // ---- updater decode: all 512 threads, cell (layer ul, col ucc, batch ub) ----
    const int ul = tid >> 8, ub = (tid >> 4) & 15, ucc = tid & 15;
    const int ucol = rs * 16 + ucc;
    float ubias[4];
    {
        const float* bi = ul ? bih1 : bih0;
        const float* bh = ul ? bhh1 : bhh0;
        #pragma unroll
        for (int g = 0; g < 4; ++g) ubias[g] = bi[g * 256 + ucol] + bh[g * 256 + ucol];
    }
    float cst = 0.f, h1last = 0.f;

    // staging decode
    const int sn = tid >> 5, sk = (tid & 31) * 8;
    const int xn = tid >> 4, xd4 = (tid & 15) * 4;

    grid.sync();   // init visible device-wide

    float4 xpre;
    if (tid < 256)
        xpre = *(const float4*)&x[((size_t)(bbase + xn) * Tsz + 0) * 64 + xd4];

    for (int s = 0; s <= Tsz; ++s) {
        const int rp = (s + 1) & 1;   // parity of h0[s-1]
        const int rq = s & 1;         // parity of h1[s-2]

        // ---- wait for superstep s-1 of this bs-group ----
        if (s > 0) {
            while (LOADX(&syn[4096 + bs * 256]) < (unsigned)s)
                __builtin_amdgcn_s_sleep(1);
        }

        // ---- stage h0[s-1], h1[s-2] (packed-uint load + v_perm unpack), x[s] ----
        {
            const unsigned* q0 = &h0u[((size_t)(rp * 256) + bbase + sn) * 256 + sk];
            const unsigned* q1 = &h1u[((size_t)(rq * 256) + bbase + sn) * 256 + sk];
            unsigned a[8], b[8];
            #pragma unroll
            for (int i = 0; i < 8; ++i) a[i] = LOADX(q0 + i);
            #pragma unroll
            for (int i = 0; i < 8; ++i) b[i] = LOADX(q1 + i);
            uint4 hi4, lo4;
            hi4.x = __builtin_amdgcn_perm(a[1], a[0], 0x07060302u);
            hi4.y = __builtin_amdgcn_perm(a[3], a[2], 0x07060302u);
            hi4.z = __builtin_amdgcn_perm(a[5], a[4], 0x07060302u);
            hi4.w = __builtin_amdgcn_perm(a[7], a[6], 0x07060302u);
            lo4.x = __builtin_amdgcn_perm(a[1], a[0], 0x05040100u);
            lo4.y = __builtin_amdgcn_perm(a[3], a[2], 0x05040100u);
            lo4.z = __builtin_amdgcn_perm(a[5], a[4], 0x05040100u);
            lo4.w = __builtin_amdgcn_perm(a[7], a[6], 0x05040100u);
            *(uint4*)&Bh[0][sn * PB0 + sk] = hi4;
            *(uint4*)&Bh[1][sn * PB0 + sk] = lo4;
            hi4.x = __builtin_amdgcn_perm(b[1], b[0], 0x07060302u);
            hi4.y = __builtin_amdgcn_perm(b[3], b[2], 0x07060302u);
            hi4.z = __builtin_amdgcn_perm(b[5], b[4], 0x07060302u);
            hi4.w = __builtin_amdgcn_perm(b[7], b[6], 0x07060302u);
            lo4.x = __builtin_amdgcn_perm(b[1], b[0], 0x05040100u);
            lo4.y = __builtin_amdgcn_perm(b[3], b[2], 0x05040100u);
            lo4.z = __builtin_amdgcn_perm(b[5], b[4], 0x05040100u);
            lo4.w = __builtin_amdgcn_perm(b[7], b[6], 0x05040100u);
            *(uint4*)&Bh[0][B1B + sn * PB1 + sk] = hi4;
            *(uint4*)&Bh[1][B1B + sn * PB1 + sk] = lo4;
        }
        if (s < Tsz && tid < 256) {
            float4 xv = xpre;
            short4v xh, xl; short2 t;
            t = split1(xv.x); xh[0] = t.x; xl[0] = t.y;
            t = split1(xv.y); xh[1] = t.x; xl[1] = t.y;
            t = split1(xv.z); xh[2] = t.x; xl[2] = t.y;
            t = split1(xv.w); xh[3] = t.x; xl[3] = t.y;
            *(short4v*)&Bh[0][xn * PB0 + 256 + xd4] = xh;
            *(short4v*)&Bh[1][xn * PB0 + 256 + xd4] = xl;
        }
        __syncthreads();   // S1: Bh staged

        // x prefetch for next superstep (drains naturally before use)
        if (tid < 256 && s + 1 < Tsz)
            xpre = *(const float4*)&x[((size_t)(bbase + xn) * Tsz + (s + 1)) * 64 + xd4];

        // ---- MFMA: full-K tile per wave, register A-frags ----
        float4v acc = {0.f, 0.f, 0.f, 0.f};
        if (w < 4) {                         // L0: K=320 over h0|x
            #pragma unroll
            for (int kc = 0; kc < 10; ++kc) {
                const int bo = bBase0 + kc * 32;
                short8 bh2 = *(const short8*)&Bh[0][bo];
                short8 bl2 = *(const short8*)&Bh[1][bo];
                acc = MFMA16(wfh[kc], bh2, acc);
                acc = MFMA16(wfh[kc], bl2, acc);
                acc = MFMA16(wfl[kc], bh2, acc);
            }
        } else {                             // L1: K=512 (h0 then h1)
            #pragma unroll
            for (int kc = 0; kc < 8; ++kc) {
                const int bo = bBase0 + kc * 32;
                short8 bh2 = *(const short8*)&Bh[0][bo];
                short8 bl2 = *(const short8*)&Bh[1][bo];
                acc = MFMA16(wfh[kc], bh2, acc);
                acc = MFMA16(wfh[kc], bl2, acc);
                acc = MFMA16(wfl[kc], bh2, acc);
            }
            #pragma unroll
            for (int kc = 8; kc < 16; ++kc) {
                const int bo = bBase1 + (kc - 8) * 32;
                short8 bh2 = *(const short8*)&Bh[0][bo];
                short8 bl2 = *(const short8*)&Bh[1][bo];
                acc = MFMA16(wfh[kc], bh2, acc);
                acc = MFMA16(wfh[kc], bl2, acc);
                acc = MFMA16(wfl[kc], bh2, acc);
            }
        }
        #pragma unroll
        for (int r = 0; r < 4; ++r)
            zf[w * 16 + quad * 4 + r][n16] = acc[r];
        __syncthreads();   // S2: zf complete

        // ---- cell update (all 512 threads own one cell) ----
        {
            const bool active = ul ? (s >= 1) : (s < Tsz);
            if (active) {
                const int mb = ul * 64 + ucc;
                float z0 = zf[mb +  0][ub] + ubias[0];
                float z1 = zf[mb + 16][ub] + ubias[1];
                float z2 = zf[mb + 32][ub] + ubias[2];
                float z3 = zf[mb + 48][ub] + ubias[3];
                float ii = sigm(z0), ff = sigm(z1);
                float gg = tanh_fast(z2), oo = sigm(z3);
                float c = ff * cst + ii * gg; cst = c;
                float hval = oo * tanh_fast(c);
                short2 hl = split1(hval);
                unsigned pk = ((unsigned)(unsigned short)hl.x << 16) |
                              (unsigned)(unsigned short)hl.y;
                if (ul) {
                    h1last = hval;
                    STOREX(&h1u[((size_t)(((s + 1) & 1) * 256) + bbase + ub) * 256 + ucol], pk);
                } else {
                    STOREX(&h0u[((size_t)((s & 1) * 256) + bbase + ub) * 256 + ucol], pk);
                }
            }
        }

        // ---- drain (S3), arrive; poll happens at top of next superstep ----
        __syncthreads();   // S3: per-wave vmcnt drained at barrier -> h stores visible
        if (tid == 0) {
            unsigned old = __hip_atomic_fetch_add(&syn[bs * 256], 1u,
                                                  __ATOMIC_RELAXED, __HIP_MEMORY_SCOPE_AGENT);
            if (old == 16u * (unsigned)(s + 1) - 1u)
                STOREX(&syn[4096 + bs * 256], (unsigned)(s + 1));
        }
    }

    // ---- epilogue: out[b] += sum_cols h1_final * Wf ----
    if (ul == 1) {
        atomicAdd(&out[bbase + ub], h1last * Wf[ucol]);
    }
}

extern "C" void kernel_launch(void* const* d_in, const int* in_sizes, int n_in,
                              void* d_out, int out_size, void* d_ws, size_t ws_size,
                              hipStream_t stream) {
    const float* x    = (const float*)d_in[0];
    const float* Wih0 = (const float*)d_in[1];
    const float* Whh0 = (const float*)d_in[2];
    const float* bih0 = (const float*)d_in[3];
    const float* bhh0 = (const float*)d_in[4];
    const float* Wih1 = (const float*)d_in[5];
    const float* Whh1 = (const float*)d_in[6];
    const float* bih1 = (const float*)d_in[7];
    const float* bhh1 = (const float*)d_in[8];
    const float* Wf   = (const float*)d_in[9];
    const float* bf   = (const float*)d_in[10];
    float* out = (float*)d_out;
    float* ws  = (float*)d_ws;   // 1 MB packed h buffers + 32 KB sync area

    void* args[] = {
        (void*)&x, (void*)&Wih0, (void*)&Whh0, (void*)&bih0, (void*)&bhh0,
        (void*)&Wih1, (void*)&Whh1, (void*)&bih1, (void*)&bhh1,
        (void*)&Wf, (void*)&bf, (void*)&out, (void*)&ws
    };
    hipLaunchCooperativeKernel((void*)lstm2_mfma, dim3(NBLK), dim3(NTHR),
                               args, 0, stream);
}